// Round 7
// baseline (1748.513 us; speedup 1.0000x reference)
//
#include <hip/hip_runtime.h>
#include <float.h>

#define N_TOK 262144
#define N_E   1024
#define E_DIM 64
#define BETA  0.25f
#define BLK   128     // threads per block == tokens per block
#define NTILE 16      // j's per tile (named accumulators m00..m15)

typedef float f32x64 __attribute__((ext_vector_type(64)));

// ---------------------------------------------------------------------------
// Bit-exact replica of numpy f32 sum-of-squares over 64 elements (register
// form, used by vq_prep). numpy reduce: out = q0 + pairwise_sum(q[1:], 63):
//   r[i] = b[i] (i=0..7); for blk=8..48 step 8: r[i] += b[blk+i];
//   res = ((r0+r1)+(r2+r3))+((r4+r5)+(r6+r7)); res += b[56..62] seq;
//   out = q0 + res;   (b[i] = v[1+i], all ops individually rounded)
// DO NOT change the op order: index bit-exactness depends on it.
// ---------------------------------------------------------------------------
__device__ __forceinline__ float np_sumsq64_v(f32x64 v)
{
    float r0 = __fmul_rn(v[1], v[1]);
    float r1 = __fmul_rn(v[2], v[2]);
    float r2 = __fmul_rn(v[3], v[3]);
    float r3 = __fmul_rn(v[4], v[4]);
    float r4 = __fmul_rn(v[5], v[5]);
    float r5 = __fmul_rn(v[6], v[6]);
    float r6 = __fmul_rn(v[7], v[7]);
    float r7 = __fmul_rn(v[8], v[8]);
#define VQ_ACC8(blk)                                                     \
    r0 = __fadd_rn(r0, __fmul_rn(v[1 + (blk)], v[1 + (blk)]));          \
    r1 = __fadd_rn(r1, __fmul_rn(v[2 + (blk)], v[2 + (blk)]));          \
    r2 = __fadd_rn(r2, __fmul_rn(v[3 + (blk)], v[3 + (blk)]));          \
    r3 = __fadd_rn(r3, __fmul_rn(v[4 + (blk)], v[4 + (blk)]));          \
    r4 = __fadd_rn(r4, __fmul_rn(v[5 + (blk)], v[5 + (blk)]));          \
    r5 = __fadd_rn(r5, __fmul_rn(v[6 + (blk)], v[6 + (blk)]));          \
    r6 = __fadd_rn(r6, __fmul_rn(v[7 + (blk)], v[7 + (blk)]));          \
    r7 = __fadd_rn(r7, __fmul_rn(v[8 + (blk)], v[8 + (blk)]))
    VQ_ACC8(8); VQ_ACC8(16); VQ_ACC8(24); VQ_ACC8(32); VQ_ACC8(40); VQ_ACC8(48);
#undef VQ_ACC8
    float tA  = __fadd_rn(__fadd_rn(r0, r1), __fadd_rn(r2, r3));
    float tB  = __fadd_rn(__fadd_rn(r4, r5), __fadd_rn(r6, r7));
    float res = __fadd_rn(tA, tB);
    res = __fadd_rn(res, __fmul_rn(v[57], v[57]));
    res = __fadd_rn(res, __fmul_rn(v[58], v[58]));
    res = __fadd_rn(res, __fmul_rn(v[59], v[59]));
    res = __fadd_rn(res, __fmul_rn(v[60], v[60]));
    res = __fadd_rn(res, __fmul_rn(v[61], v[61]));
    res = __fadd_rn(res, __fmul_rn(v[62], v[62]));
    res = __fadd_rn(res, __fmul_rn(v[63], v[63]));
    return __fadd_rn(__fmul_rn(v[0], v[0]), res);
}

// ---------------------------------------------------------------------------
// Prologue: scn[j] = np-f32 ||cb[j]||^2; zero the loss slot (harness does not
// re-poison d_out between replays; ordered before vq_main on the stream).
// ---------------------------------------------------------------------------
__global__ __launch_bounds__(256) void vq_prep(const float* __restrict__ cb,
                                               float* __restrict__ scn,
                                               float* __restrict__ loss_slot)
{
    int j = blockIdx.x * 256 + threadIdx.x;
    if (j < N_E) {
        const float* c = cb + (size_t)j * E_DIM;
        f32x64 cr;
#pragma unroll
        for (int k = 0; k < E_DIM; k += 4) {
            float4 v = *(const float4*)(c + k);
            cr[k] = v.x; cr[k + 1] = v.y; cr[k + 2] = v.z; cr[k + 3] = v.w;
        }
        scn[j] = np_sumsq64_v(cr);
    }
    if (blockIdx.x == 0 && threadIdx.x == 0) *loss_slot = 0.f;
}

// ---------------------------------------------------------------------------
// Main. One token per thread; x-row lives in LDS column At[k][t] (thread-
// private: each thread reads only its own column -> no barriers, and LDS
// acts as explicit register extension, defeating the 64-VGPR allocator cap
// that spilled rounds 3-6). Conflict-free: consecutive lanes hit consecutive
// banks; all ds_reads share one vaddr (t*4) + immediate offsets.
// j-tiled (16) x k-chunked (16): only 16 x-floats + 16 accumulators live.
// Bit-exact np f32 pipeline (frozen from passing r3):
//   m_j: single fmaf chain, k = 0..63 strictly ascending (chunks sequential)
//   d_j = f32( f32(sx + scn_j) - f32(2*m_j) ); argmin strict <, j ascending.
// Codebook operands are wave-uniform -> s_load broadcasts (SGPR).
// ---------------------------------------------------------------------------
__global__ __launch_bounds__(BLK)
void vq_main(const float* __restrict__ x,
             const float* __restrict__ cb,
             const float* __restrict__ scn,
             float* __restrict__ xq_out,
             float* __restrict__ loss_out,
             float* __restrict__ idx_out)
{
    __shared__ float At[E_DIM][BLK];   // 32 KB, transposed x tile
    __shared__ float red[2];

    const int t   = threadIdx.x;
    const int tok = blockIdx.x * BLK + t;

#define XT(k) At[(k)][t]

    // ---- stage own x-row into own LDS column (no cross-thread use) ----
    {
        const float* xrow = x + (size_t)tok * E_DIM;
#pragma unroll
        for (int c = 0; c < 16; ++c) {
            float4 v = *(const float4*)(xrow + 4 * c);
            At[4 * c + 0][t] = v.x;
            At[4 * c + 1][t] = v.y;
            At[4 * c + 2][t] = v.z;
            At[4 * c + 3][t] = v.w;
        }
    }

    // ---- sx: numpy pairwise order, streamed from LDS (frozen op order) ----
    float sx;
    {
#define Q(k) __fmul_rn(XT(k), XT(k))
        float r0 = Q(1), r1 = Q(2), r2 = Q(3), r3 = Q(4);
        float r4 = Q(5), r5 = Q(6), r6 = Q(7), r7 = Q(8);
#define SACC(b)                                  \
        r0 = __fadd_rn(r0, Q(1 + (b)));          \
        r1 = __fadd_rn(r1, Q(2 + (b)));          \
        r2 = __fadd_rn(r2, Q(3 + (b)));          \
        r3 = __fadd_rn(r3, Q(4 + (b)));          \
        r4 = __fadd_rn(r4, Q(5 + (b)));          \
        r5 = __fadd_rn(r5, Q(6 + (b)));          \
        r6 = __fadd_rn(r6, Q(7 + (b)));          \
        r7 = __fadd_rn(r7, Q(8 + (b)));
        SACC(8) SACC(16) SACC(24) SACC(32) SACC(40) SACC(48)
#undef SACC
        float tA  = __fadd_rn(__fadd_rn(r0, r1), __fadd_rn(r2, r3));
        float tB  = __fadd_rn(__fadd_rn(r4, r5), __fadd_rn(r6, r7));
        float res = __fadd_rn(tA, tB);
        res = __fadd_rn(res, Q(57));
        res = __fadd_rn(res, Q(58));
        res = __fadd_rn(res, Q(59));
        res = __fadd_rn(res, Q(60));
        res = __fadd_rn(res, Q(61));
        res = __fadd_rn(res, Q(62));
        res = __fadd_rn(res, Q(63));
        sx = __fadd_rn(Q(0), res);
#undef Q
    }

    float dmin = FLT_MAX;
    int   imin = 0;

    // 4 interleaved chains per group: ILP 4 covers FMA latency; per-chain
    // k order is strictly ascending (bit-exact).
#define FMAQ(xv, kk, ma, mb, mc, md)             \
    ma = fmaf(xv, p0[kk], ma);                   \
    mb = fmaf(xv, p1[kk], mb);                   \
    mc = fmaf(xv, p2[kk], mc);                   \
    md = fmaf(xv, p3[kk], md);

#define GROUP(jbase, kc, ma, mb, mc, md) do {                        \
    const float* p0 = cb + (size_t)(jbase) * E_DIM + (kc);           \
    const float* p1 = p0 + E_DIM;                                    \
    const float* p2 = p1 + E_DIM;                                    \
    const float* p3 = p2 + E_DIM;                                    \
    FMAQ(x0, 0, ma, mb, mc, md)  FMAQ(x1, 1, ma, mb, mc, md)         \
    FMAQ(x2, 2, ma, mb, mc, md)  FMAQ(x3, 3, ma, mb, mc, md)         \
    FMAQ(x4, 4, ma, mb, mc, md)  FMAQ(x5, 5, ma, mb, mc, md)         \
    FMAQ(x6, 6, ma, mb, mc, md)  FMAQ(x7, 7, ma, mb, mc, md)         \
    FMAQ(x8, 8, ma, mb, mc, md)  FMAQ(x9, 9, ma, mb, mc, md)         \
    FMAQ(x10, 10, ma, mb, mc, md) FMAQ(x11, 11, ma, mb, mc, md)      \
    FMAQ(x12, 12, ma, mb, mc, md) FMAQ(x13, 13, ma, mb, mc, md)      \
    FMAQ(x14, 14, ma, mb, mc, md) FMAQ(x15, 15, ma, mb, mc, md)      \
} while (0)

#define CHUNK(kc) do {                                               \
    const float x0  = XT((kc) + 0),  x1  = XT((kc) + 1);             \
    const float x2  = XT((kc) + 2),  x3  = XT((kc) + 3);             \
    const float x4  = XT((kc) + 4),  x5  = XT((kc) + 5);             \
    const float x6  = XT((kc) + 6),  x7  = XT((kc) + 7);             \
    const float x8  = XT((kc) + 8),  x9  = XT((kc) + 9);             \
    const float x10 = XT((kc) + 10), x11 = XT((kc) + 11);            \
    const float x12 = XT((kc) + 12), x13 = XT((kc) + 13);            \
    const float x14 = XT((kc) + 14), x15 = XT((kc) + 15);            \
    GROUP(j0 + 0,  (kc), m00, m01, m02, m03);                        \
    GROUP(j0 + 4,  (kc), m04, m05, m06, m07);                        \
    GROUP(j0 + 8,  (kc), m08, m09, m10, m11);                        \
    GROUP(j0 + 12, (kc), m12, m13, m14, m15);                        \
} while (0)

#define DCHK(jl, mv) {                                                      \
    float d = __fsub_rn(__fadd_rn(sx, scn[j0 + (jl)]), __fmul_rn(2.0f, mv)); \
    if (d < dmin) { dmin = d; imin = j0 + (jl); }                           \
}

    for (int j0 = 0; j0 < N_E; j0 += NTILE) {
        float m00 = 0.f, m01 = 0.f, m02 = 0.f, m03 = 0.f;
        float m04 = 0.f, m05 = 0.f, m06 = 0.f, m07 = 0.f;
        float m08 = 0.f, m09 = 0.f, m10 = 0.f, m11 = 0.f;
        float m12 = 0.f, m13 = 0.f, m14 = 0.f, m15 = 0.f;
        CHUNK(0); CHUNK(16); CHUNK(32); CHUNK(48);
        DCHK(0, m00)  DCHK(1, m01)  DCHK(2, m02)  DCHK(3, m03)
        DCHK(4, m04)  DCHK(5, m05)  DCHK(6, m06)  DCHK(7, m07)
        DCHK(8, m08)  DCHK(9, m09)  DCHK(10, m10) DCHK(11, m11)
        DCHK(12, m12) DCHK(13, m13) DCHK(14, m14) DCHK(15, m15)
    }

    // ---- epilogue: gather winning row (L2-hot), write x_q, fused loss ----
    float lsum = 0.f;
    {
        const float* cmin = cb + (size_t)imin * E_DIM;   // per-lane address
        float*       xq   = xq_out + (size_t)tok * E_DIM;
#pragma unroll
        for (int c = 0; c < 16; ++c) {
            float4 cv = *(const float4*)(cmin + 4 * c);
            *(float4*)(xq + 4 * c) = cv;                 // fwd x_q_st == x_q
            float e0 = cv.x - XT(4 * c + 0);
            float e1 = cv.y - XT(4 * c + 1);
            float e2 = cv.z - XT(4 * c + 2);
            float e3 = cv.w - XT(4 * c + 3);
            lsum = fmaf(e0, e0, lsum);
            lsum = fmaf(e1, e1, lsum);
            lsum = fmaf(e2, e2, lsum);
            lsum = fmaf(e3, e3, lsum);
        }
    }
    idx_out[tok] = (float)imin;   // exact integer in f32

    // Loss: 64-lane shuffle tree, cross-wave via LDS, one atomic per block.
    for (int m = 1; m < 64; m <<= 1) lsum += __shfl_xor(lsum, m, 64);
    if ((t & 63) == 0) red[t >> 6] = lsum;
    __syncthreads();
    if (t == 0) {
        float part = red[0] + red[1];
        const float scale = (1.0f + BETA) / ((float)N_TOK * (float)E_DIM);
        atomicAdd(loss_out, part * scale);
    }
#undef XT
#undef FMAQ
#undef GROUP
#undef CHUNK
#undef DCHK
}

extern "C" void kernel_launch(void* const* d_in, const int* in_sizes, int n_in,
                              void* d_out, int out_size, void* d_ws, size_t ws_size,
                              hipStream_t stream)
{
    const float* x  = (const float*)d_in[0];   // [262144, 64] f32
    const float* cb = (const float*)d_in[1];   // [1024, 64]   f32

    float* out  = (float*)d_out;
    float* xq   = out;                              // 262144*64 floats
    float* loss = out + (size_t)N_TOK * E_DIM;      // 1 float
    float* idx  = loss + 1;                         // 262144 floats

    float* scn = (float*)d_ws;                      // 1024 floats scratch

    vq_prep<<<N_E / 256, 256, 0, stream>>>(cb, scn, loss);
    vq_main<<<N_TOK / BLK, BLK, 0, stream>>>(x, cb, scn, xq, loss, idx);
}

// Round 8
// 752.803 us; speedup vs baseline: 2.3227x; 2.3227x over previous
//
#include <hip/hip_runtime.h>
#include <float.h>

#define N_TOK 262144
#define N_E   1024
#define E_DIM 64
#define BETA  0.25f
#define BLK   256     // threads per block == tokens per block
#define NREG  40      // x[0..39] in named VGPRs
#define NLDS  24      // x[40..63] in LDS column (24.6 KB/block -> 6 blk/CU)

typedef float f32x64 __attribute__((ext_vector_type(64)));

// ---------------------------------------------------------------------------
// Bit-exact replica of numpy f32 sum-of-squares over 64 elements (register
// form, used by vq_prep). numpy reduce: out = q0 + pairwise_sum(q[1:], 63):
//   r[i] = b[i] (i=0..7); for blk=8..48 step 8: r[i] += b[blk+i];
//   res = ((r0+r1)+(r2+r3))+((r4+r5)+(r6+r7)); res += b[56..62] seq;
//   out = q0 + res;   (b[i] = v[1+i], all ops individually rounded)
// DO NOT change the op order: index bit-exactness depends on it.
// ---------------------------------------------------------------------------
__device__ __forceinline__ float np_sumsq64_v(f32x64 v)
{
    float r0 = __fmul_rn(v[1], v[1]);
    float r1 = __fmul_rn(v[2], v[2]);
    float r2 = __fmul_rn(v[3], v[3]);
    float r3 = __fmul_rn(v[4], v[4]);
    float r4 = __fmul_rn(v[5], v[5]);
    float r5 = __fmul_rn(v[6], v[6]);
    float r6 = __fmul_rn(v[7], v[7]);
    float r7 = __fmul_rn(v[8], v[8]);
#define VQ_ACC8(blk)                                                     \
    r0 = __fadd_rn(r0, __fmul_rn(v[1 + (blk)], v[1 + (blk)]));          \
    r1 = __fadd_rn(r1, __fmul_rn(v[2 + (blk)], v[2 + (blk)]));          \
    r2 = __fadd_rn(r2, __fmul_rn(v[3 + (blk)], v[3 + (blk)]));          \
    r3 = __fadd_rn(r3, __fmul_rn(v[4 + (blk)], v[4 + (blk)]));          \
    r4 = __fadd_rn(r4, __fmul_rn(v[5 + (blk)], v[5 + (blk)]));          \
    r5 = __fadd_rn(r5, __fmul_rn(v[6 + (blk)], v[6 + (blk)]));          \
    r6 = __fadd_rn(r6, __fmul_rn(v[7 + (blk)], v[7 + (blk)]));          \
    r7 = __fadd_rn(r7, __fmul_rn(v[8 + (blk)], v[8 + (blk)]))
    VQ_ACC8(8); VQ_ACC8(16); VQ_ACC8(24); VQ_ACC8(32); VQ_ACC8(40); VQ_ACC8(48);
#undef VQ_ACC8
    float tA  = __fadd_rn(__fadd_rn(r0, r1), __fadd_rn(r2, r3));
    float tB  = __fadd_rn(__fadd_rn(r4, r5), __fadd_rn(r6, r7));
    float res = __fadd_rn(tA, tB);
    res = __fadd_rn(res, __fmul_rn(v[57], v[57]));
    res = __fadd_rn(res, __fmul_rn(v[58], v[58]));
    res = __fadd_rn(res, __fmul_rn(v[59], v[59]));
    res = __fadd_rn(res, __fmul_rn(v[60], v[60]));
    res = __fadd_rn(res, __fmul_rn(v[61], v[61]));
    res = __fadd_rn(res, __fmul_rn(v[62], v[62]));
    res = __fadd_rn(res, __fmul_rn(v[63], v[63]));
    return __fadd_rn(__fmul_rn(v[0], v[0]), res);
}

__global__ __launch_bounds__(256) void vq_prep(const float* __restrict__ cb,
                                               float* __restrict__ scn,
                                               float* __restrict__ loss_slot)
{
    int j = blockIdx.x * 256 + threadIdx.x;
    if (j < N_E) {
        const float* c = cb + (size_t)j * E_DIM;
        f32x64 cr;
#pragma unroll
        for (int k = 0; k < E_DIM; k += 4) {
            float4 v = *(const float4*)(c + k);
            cr[k] = v.x; cr[k + 1] = v.y; cr[k + 2] = v.z; cr[k + 3] = v.w;
        }
        scn[j] = np_sumsq64_v(cr);
    }
    if (blockIdx.x == 0 && threadIdx.x == 0) *loss_slot = 0.f;
}

// ---------------------------------------------------------------------------
// Main. One token/thread. Hybrid x-placement: k=0..39 in named VGPRs (no
// array -> allocator cannot demote), k=40..63 in a thread-private LDS column
// (single vaddr t*4 + immediate offsets, 2-way bank alias = free, no
// barriers). j-quad: 4 interleaved chains reuse each x-operand 4x (LDS pipe
// ~40% busy at full VALU). Live VGPRs ~58 < the 64 cap that spilled r3-r6.
// Bit-exact np f32 pipeline (frozen from passing r3/r6):
//   m_j: single fmaf chain, k = 0..63 strictly ascending
//   d_j = f32( f32(sx + scn_j) - f32(2*m_j) ); argmin strict <, j ascending.
// ---------------------------------------------------------------------------
__global__ __launch_bounds__(BLK)
void vq_main(const float* __restrict__ x,
             const float* __restrict__ cb,
             const float* __restrict__ scn,
             float* __restrict__ xq_out,
             float* __restrict__ loss_out,
             float* __restrict__ idx_out)
{
    __shared__ float At[NLDS][BLK];   // x[40..63] columns, 24.6 KB
    __shared__ float red[4];

    const int t   = threadIdx.x;
    const int tok = blockIdx.x * BLK + t;

    float x0,  x1,  x2,  x3,  x4,  x5,  x6,  x7,  x8,  x9;
    float x10, x11, x12, x13, x14, x15, x16, x17, x18, x19;
    float x20, x21, x22, x23, x24, x25, x26, x27, x28, x29;
    float x30, x31, x32, x33, x34, x35, x36, x37, x38, x39;

#define XV_0 x0
#define XV_1 x1
#define XV_2 x2
#define XV_3 x3
#define XV_4 x4
#define XV_5 x5
#define XV_6 x6
#define XV_7 x7
#define XV_8 x8
#define XV_9 x9
#define XV_10 x10
#define XV_11 x11
#define XV_12 x12
#define XV_13 x13
#define XV_14 x14
#define XV_15 x15
#define XV_16 x16
#define XV_17 x17
#define XV_18 x18
#define XV_19 x19
#define XV_20 x20
#define XV_21 x21
#define XV_22 x22
#define XV_23 x23
#define XV_24 x24
#define XV_25 x25
#define XV_26 x26
#define XV_27 x27
#define XV_28 x28
#define XV_29 x29
#define XV_30 x30
#define XV_31 x31
#define XV_32 x32
#define XV_33 x33
#define XV_34 x34
#define XV_35 x35
#define XV_36 x36
#define XV_37 x37
#define XV_38 x38
#define XV_39 x39
#define XV_40 At[0][t]
#define XV_41 At[1][t]
#define XV_42 At[2][t]
#define XV_43 At[3][t]
#define XV_44 At[4][t]
#define XV_45 At[5][t]
#define XV_46 At[6][t]
#define XV_47 At[7][t]
#define XV_48 At[8][t]
#define XV_49 At[9][t]
#define XV_50 At[10][t]
#define XV_51 At[11][t]
#define XV_52 At[12][t]
#define XV_53 At[13][t]
#define XV_54 At[14][t]
#define XV_55 At[15][t]
#define XV_56 At[16][t]
#define XV_57 At[17][t]
#define XV_58 At[18][t]
#define XV_59 At[19][t]
#define XV_60 At[20][t]
#define XV_61 At[21][t]
#define XV_62 At[22][t]
#define XV_63 At[23][t]
#define XV(k) XV_##k

    // ---- stage x row: 10 float4 -> regs, 6 float4 -> own LDS column ----
    {
        const float* xrow = x + (size_t)tok * E_DIM;
        float4 q;
        q = *(const float4*)(xrow +  0); x0  = q.x; x1  = q.y; x2  = q.z; x3  = q.w;
        q = *(const float4*)(xrow +  4); x4  = q.x; x5  = q.y; x6  = q.z; x7  = q.w;
        q = *(const float4*)(xrow +  8); x8  = q.x; x9  = q.y; x10 = q.z; x11 = q.w;
        q = *(const float4*)(xrow + 12); x12 = q.x; x13 = q.y; x14 = q.z; x15 = q.w;
        q = *(const float4*)(xrow + 16); x16 = q.x; x17 = q.y; x18 = q.z; x19 = q.w;
        q = *(const float4*)(xrow + 20); x20 = q.x; x21 = q.y; x22 = q.z; x23 = q.w;
        q = *(const float4*)(xrow + 24); x24 = q.x; x25 = q.y; x26 = q.z; x27 = q.w;
        q = *(const float4*)(xrow + 28); x28 = q.x; x29 = q.y; x30 = q.z; x31 = q.w;
        q = *(const float4*)(xrow + 32); x32 = q.x; x33 = q.y; x34 = q.z; x35 = q.w;
        q = *(const float4*)(xrow + 36); x36 = q.x; x37 = q.y; x38 = q.z; x39 = q.w;
        q = *(const float4*)(xrow + 40); At[0][t]  = q.x; At[1][t]  = q.y; At[2][t]  = q.z; At[3][t]  = q.w;
        q = *(const float4*)(xrow + 44); At[4][t]  = q.x; At[5][t]  = q.y; At[6][t]  = q.z; At[7][t]  = q.w;
        q = *(const float4*)(xrow + 48); At[8][t]  = q.x; At[9][t]  = q.y; At[10][t] = q.z; At[11][t] = q.w;
        q = *(const float4*)(xrow + 52); At[12][t] = q.x; At[13][t] = q.y; At[14][t] = q.z; At[15][t] = q.w;
        q = *(const float4*)(xrow + 56); At[16][t] = q.x; At[17][t] = q.y; At[18][t] = q.z; At[19][t] = q.w;
        q = *(const float4*)(xrow + 60); At[20][t] = q.x; At[21][t] = q.y; At[22][t] = q.z; At[23][t] = q.w;
    }

    // ---- sx: numpy pairwise order (frozen) ----
    float sx;
    {
#define Q(k) __fmul_rn(XV(k), XV(k))
        float r0 = Q(1), r1 = Q(2), r2 = Q(3), r3 = Q(4);
        float r4 = Q(5), r5 = Q(6), r6 = Q(7), r7 = Q(8);
        r0 = __fadd_rn(r0, Q(9));  r1 = __fadd_rn(r1, Q(10));
        r2 = __fadd_rn(r2, Q(11)); r3 = __fadd_rn(r3, Q(12));
        r4 = __fadd_rn(r4, Q(13)); r5 = __fadd_rn(r5, Q(14));
        r6 = __fadd_rn(r6, Q(15)); r7 = __fadd_rn(r7, Q(16));
        r0 = __fadd_rn(r0, Q(17)); r1 = __fadd_rn(r1, Q(18));
        r2 = __fadd_rn(r2, Q(19)); r3 = __fadd_rn(r3, Q(20));
        r4 = __fadd_rn(r4, Q(21)); r5 = __fadd_rn(r5, Q(22));
        r6 = __fadd_rn(r6, Q(23)); r7 = __fadd_rn(r7, Q(24));
        r0 = __fadd_rn(r0, Q(25)); r1 = __fadd_rn(r1, Q(26));
        r2 = __fadd_rn(r2, Q(27)); r3 = __fadd_rn(r3, Q(28));
        r4 = __fadd_rn(r4, Q(29)); r5 = __fadd_rn(r5, Q(30));
        r6 = __fadd_rn(r6, Q(31)); r7 = __fadd_rn(r7, Q(32));
        r0 = __fadd_rn(r0, Q(33)); r1 = __fadd_rn(r1, Q(34));
        r2 = __fadd_rn(r2, Q(35)); r3 = __fadd_rn(r3, Q(36));
        r4 = __fadd_rn(r4, Q(37)); r5 = __fadd_rn(r5, Q(38));
        r6 = __fadd_rn(r6, Q(39)); r7 = __fadd_rn(r7, Q(40));
        r0 = __fadd_rn(r0, Q(41)); r1 = __fadd_rn(r1, Q(42));
        r2 = __fadd_rn(r2, Q(43)); r3 = __fadd_rn(r3, Q(44));
        r4 = __fadd_rn(r4, Q(45)); r5 = __fadd_rn(r5, Q(46));
        r6 = __fadd_rn(r6, Q(47)); r7 = __fadd_rn(r7, Q(48));
        r0 = __fadd_rn(r0, Q(49)); r1 = __fadd_rn(r1, Q(50));
        r2 = __fadd_rn(r2, Q(51)); r3 = __fadd_rn(r3, Q(52));
        r4 = __fadd_rn(r4, Q(53)); r5 = __fadd_rn(r5, Q(54));
        r6 = __fadd_rn(r6, Q(55)); r7 = __fadd_rn(r7, Q(56));
        float tA  = __fadd_rn(__fadd_rn(r0, r1), __fadd_rn(r2, r3));
        float tB  = __fadd_rn(__fadd_rn(r4, r5), __fadd_rn(r6, r7));
        float res = __fadd_rn(tA, tB);
        res = __fadd_rn(res, Q(57));
        res = __fadd_rn(res, Q(58));
        res = __fadd_rn(res, Q(59));
        res = __fadd_rn(res, Q(60));
        res = __fadd_rn(res, Q(61));
        res = __fadd_rn(res, Q(62));
        res = __fadd_rn(res, Q(63));
        sx = __fadd_rn(Q(0), res);
#undef Q
    }

    float dmin = FLT_MAX;
    int   imin = 0;

    // per-k step: 4 fmaf (one per j-chain); per-chain k order strictly asc.
#define FK(k) {                                   \
        const float xv = XV(k);                   \
        m0 = fmaf(xv, c0[k], m0);                 \
        m1 = fmaf(xv, c1[k], m1);                 \
        m2 = fmaf(xv, c2[k], m2);                 \
        m3 = fmaf(xv, c3[k], m3);                 \
    }

#pragma clang loop unroll(disable)
    for (int j0 = 0; j0 < N_E; j0 += 4) {
        const float* c0 = cb + (size_t)j0 * E_DIM;   // wave-uniform
        const float* c1 = c0 + E_DIM;
        const float* c2 = c1 + E_DIM;
        const float* c3 = c2 + E_DIM;
        float m0 = 0.f, m1 = 0.f, m2 = 0.f, m3 = 0.f;
        FK(0)  FK(1)  FK(2)  FK(3)  FK(4)  FK(5)  FK(6)  FK(7)
        FK(8)  FK(9)  FK(10) FK(11) FK(12) FK(13) FK(14) FK(15)
        FK(16) FK(17) FK(18) FK(19) FK(20) FK(21) FK(22) FK(23)
        FK(24) FK(25) FK(26) FK(27) FK(28) FK(29) FK(30) FK(31)
        FK(32) FK(33) FK(34) FK(35) FK(36) FK(37) FK(38) FK(39)
        FK(40) FK(41) FK(42) FK(43) FK(44) FK(45) FK(46) FK(47)
        FK(48) FK(49) FK(50) FK(51) FK(52) FK(53) FK(54) FK(55)
        FK(56) FK(57) FK(58) FK(59) FK(60) FK(61) FK(62) FK(63)
        float d0 = __fsub_rn(__fadd_rn(sx, scn[j0    ]), __fmul_rn(2.0f, m0));
        float d1 = __fsub_rn(__fadd_rn(sx, scn[j0 + 1]), __fmul_rn(2.0f, m1));
        float d2 = __fsub_rn(__fadd_rn(sx, scn[j0 + 2]), __fmul_rn(2.0f, m2));
        float d3 = __fsub_rn(__fadd_rn(sx, scn[j0 + 3]), __fmul_rn(2.0f, m3));
        if (d0 < dmin) { dmin = d0; imin = j0; }
        if (d1 < dmin) { dmin = d1; imin = j0 + 1; }
        if (d2 < dmin) { dmin = d2; imin = j0 + 2; }
        if (d3 < dmin) { dmin = d3; imin = j0 + 3; }
    }
#undef FK

    // ---- epilogue: gather winning row (L2-hot), write x_q, fused loss ----
    float lsum = 0.f;
    {
        const float* cmin = cb + (size_t)imin * E_DIM;   // per-lane address
        float*       xq   = xq_out + (size_t)tok * E_DIM;
        float4 cv; float e;
#define LQ(base, a, b, c, d)                                        \
        cv = *(const float4*)(cmin + (base));                       \
        *(float4*)(xq + (base)) = cv;                               \
        e = cv.x - XV(a); lsum = fmaf(e, e, lsum);                  \
        e = cv.y - XV(b); lsum = fmaf(e, e, lsum);                  \
        e = cv.z - XV(c); lsum = fmaf(e, e, lsum);                  \
        e = cv.w - XV(d); lsum = fmaf(e, e, lsum);
        LQ(0,  0, 1, 2, 3)    LQ(4,  4, 5, 6, 7)
        LQ(8,  8, 9, 10, 11)  LQ(12, 12, 13, 14, 15)
        LQ(16, 16, 17, 18, 19) LQ(20, 20, 21, 22, 23)
        LQ(24, 24, 25, 26, 27) LQ(28, 28, 29, 30, 31)
        LQ(32, 32, 33, 34, 35) LQ(36, 36, 37, 38, 39)
        LQ(40, 40, 41, 42, 43) LQ(44, 44, 45, 46, 47)
        LQ(48, 48, 49, 50, 51) LQ(52, 52, 53, 54, 55)
        LQ(56, 56, 57, 58, 59) LQ(60, 60, 61, 62, 63)
#undef LQ
    }
    idx_out[tok] = (float)imin;   // exact integer in f32

    // Loss: 64-lane shuffle tree, cross-wave via LDS, one atomic per block.
    for (int m = 1; m < 64; m <<= 1) lsum += __shfl_xor(lsum, m, 64);
    if ((t & 63) == 0) red[t >> 6] = lsum;
    __syncthreads();
    if (t == 0) {
        float part = (red[0] + red[1]) + (red[2] + red[3]);
        const float scale = (1.0f + BETA) / ((float)N_TOK * (float)E_DIM);
        atomicAdd(loss_out, part * scale);
    }
}

extern "C" void kernel_launch(void* const* d_in, const int* in_sizes, int n_in,
                              void* d_out, int out_size, void* d_ws, size_t ws_size,
                              hipStream_t stream)
{
    const float* x  = (const float*)d_in[0];   // [262144, 64] f32
    const float* cb = (const float*)d_in[1];   // [1024, 64]   f32

    float* out  = (float*)d_out;
    float* xq   = out;                              // 262144*64 floats
    float* loss = out + (size_t)N_TOK * E_DIM;      // 1 float
    float* idx  = loss + 1;                         // 262144 floats

    float* scn = (float*)d_ws;                      // 1024 floats scratch

    vq_prep<<<N_E / 256, 256, 0, stream>>>(cb, scn, loss);
    vq_main<<<N_TOK / BLK, BLK, 0, stream>>>(x, cb, scn, xq, loss, idx);
}